// Round 3
// baseline (769.803 us; speedup 1.0000x reference)
//
#include <hip/hip_runtime.h>
#include <cstdint>

typedef __bf16 bf16;
typedef bf16 bf16x8 __attribute__((ext_vector_type(8)));
typedef float f32x4 __attribute__((ext_vector_type(4)));

#define S_LEN   16384
#define HID     1280
#define NHEAD   16
#define HD      80
#define HDP     96
#define CHUNK   1024
#define NCHUNKS 16

// workspace element offsets (bf16 elements)
#define OFF_XB     0LL           // x bf16            [16384][1280]
#define OFF_WQKV   20971520LL    // w_qkv bf16        [3840][1280]
#define OFF_WPROJ  25886720LL    // w_proj bf16       [1280][1280]
#define OFF_QPAD   27525120LL    // q bf16 padded     [16384][16][96]
#define OFF_KPAD   52690944LL    // k bf16 padded     [16384][16][96]
#define OFF_VT     77856768LL    // v^T bf16          [16][16][80][1024]
#define OFF_ATTN   98828288LL    // attn out bf16     [16384][1280]

// global -> LDS direct copy, 16 B per lane; lane i lands at base + i*16.
__device__ __forceinline__ void gl_lds16(const void* g, void* l) {
  __builtin_amdgcn_global_load_lds(
      (const __attribute__((address_space(1))) unsigned int*)g,
      (__attribute__((address_space(3))) unsigned int*)l, 16, 0, 0);
}

// ---------------------------------------------------------------------------
// Kernel 1: fp32 -> bf16 conversion + zero-fill of q/k pad dims (80..95)
// ---------------------------------------------------------------------------
__global__ void convert_kernel(const float* __restrict__ x,
                               const float* __restrict__ wqkv,
                               const float* __restrict__ wproj,
                               bf16* __restrict__ ws) {
  const long long N1 = 20971520LL;
  const long long N2 = 4915200LL;
  const long long N3 = 1638400LL;
  const long long N4 = 4194304LL;
  long long i = ((long long)blockIdx.x * 256 + threadIdx.x) << 2;
  if (i < N1) {
    float4 v = *(const float4*)(x + i);
    bf16* o = ws + OFF_XB + i;
    o[0] = (bf16)v.x; o[1] = (bf16)v.y; o[2] = (bf16)v.z; o[3] = (bf16)v.w;
    return;
  }
  i -= N1;
  if (i < N2) {
    float4 v = *(const float4*)(wqkv + i);
    bf16* o = ws + OFF_WQKV + i;
    o[0] = (bf16)v.x; o[1] = (bf16)v.y; o[2] = (bf16)v.z; o[3] = (bf16)v.w;
    return;
  }
  i -= N2;
  if (i < N3) {
    float4 v = *(const float4*)(wproj + i);
    bf16* o = ws + OFF_WPROJ + i;
    o[0] = (bf16)v.x; o[1] = (bf16)v.y; o[2] = (bf16)v.z; o[3] = (bf16)v.w;
    return;
  }
  i -= N3;
  if (i < N4) {
    long long g = i >> 4; int j = (int)(i & 15);
    *(uint2*)(ws + OFF_QPAD + g * HDP + HD + j) = make_uint2(0u, 0u);
    return;
  }
  i -= N4;
  if (i < N4) {
    long long g = i >> 4; int j = (int)(i & 15);
    *(uint2*)(ws + OFF_KPAD + g * HDP + HD + j) = make_uint2(0u, 0u);
    return;
  }
}

// ---------------------------------------------------------------------------
// Kernels 2 & 5: bf16 GEMM C = A @ B^T (+bias). 128x128 tile, BK=32,
// DOUBLE-BUFFERED global_load_lds staging (one barrier per K-step; the
// vmcnt(0) drain at the barrier now waits on loads that overlapped a full
// compute phase). LDS 2x20480 B -> 4 blocks/CU. Padded stride-40 rows via
// chunk remap (chunk ci -> row ci/5, col (ci%5)*16 B, 5th chunk = pad).
// ---------------------------------------------------------------------------
template <int MODE>
__global__ __launch_bounds__(256, 4) void gemm_bt_kernel(
    const bf16* __restrict__ A, const bf16* __restrict__ B,
    const float* __restrict__ bias, bf16* __restrict__ ws,
    float* __restrict__ outF) {
  __shared__ __align__(16) bf16 ABs[2][10240];  // A[128][40] then B[128][40]
  const int tid = threadIdx.x;
  const int lane = tid & 63;
  const int w = tid >> 6;
  const int wr = w >> 1, wc = w & 1;
  const int quad = lane >> 4, l16 = lane & 15;
  const long long m0 = (long long)blockIdx.y * 128;
  const long long n0 = (long long)blockIdx.x * 128;

  // per-thread staging sources for the 5 chunk rounds
  const bf16* gsrc[5];
#pragma unroll
  for (int j = 0; j < 5; ++j) {
    int ci = tid + j * 256;
    int row = ci / 5;
    int cb = (ci - row * 5) * 16;       // 0,16,32,48,64 (64 = pad)
    int ce = (cb == 64) ? 0 : (cb >> 1);
    long long grow = (row < 128) ? (m0 + row) : (n0 + row - 128);
    const bf16* base = (row < 128) ? A : B;
    gsrc[j] = base + grow * 1280 + ce;
  }
  const int ldst = (w << 6) * 16;  // wave-uniform LDS chunk base (byte)

  // prologue: stage k0=0 into buffer 0
#pragma unroll
  for (int j = 0; j < 5; ++j)
    gl_lds16(gsrc[j], (char*)ABs[0] + j * 4096 + ldst);

  f32x4 acc[4][4] = {};

  for (int k0 = 0; k0 < 1280; k0 += 32) {
    const int cur = (k0 >> 5) & 1;
    __syncthreads();  // drains vmcnt -> buf[cur] ready; all waves done reading buf[cur^1]
    if (k0 + 32 < 1280) {
#pragma unroll
      for (int j = 0; j < 5; ++j)
        gl_lds16(gsrc[j] + k0 + 32, (char*)ABs[cur ^ 1] + j * 4096 + ldst);
    }
    const bf16* As = ABs[cur];
    const bf16* Bs = ABs[cur] + 5120;
    bf16x8 af[4], bfr[4];
#pragma unroll
    for (int it = 0; it < 4; ++it)
      af[it] = *(const bf16x8*)(As + (wr * 64 + it * 16 + l16) * 40 + quad * 8);
#pragma unroll
    for (int jt = 0; jt < 4; ++jt)
      bfr[jt] = *(const bf16x8*)(Bs + (wc * 64 + jt * 16 + l16) * 40 + quad * 8);
#pragma unroll
    for (int it = 0; it < 4; ++it)
#pragma unroll
      for (int jt = 0; jt < 4; ++jt)
        acc[it][jt] = __builtin_amdgcn_mfma_f32_16x16x32_bf16(
            af[it], bfr[jt], acc[it][jt], 0, 0, 0);
  }

  if (MODE == 0) {
    bf16* qpad = ws + OFF_QPAD;
    bf16* kpad = ws + OFF_KPAD;
    bf16* vt = ws + OFF_VT;
#pragma unroll
    for (int jt = 0; jt < 4; ++jt) {
      int n = (int)n0 + wc * 64 + jt * 16 + l16;
      float bv = bias[n];
      int part = n / HID;
      int idx = n - part * HID;
      int h = idx / HD;
      int d = idx - h * HD;
#pragma unroll
      for (int it = 0; it < 4; ++it) {
#pragma unroll
        for (int r = 0; r < 4; ++r) {
          long long m = m0 + wr * 64 + it * 16 + quad * 4 + r;
          float v = acc[it][jt][r] + bv;
          if (part == 0) {
            qpad[(m * NHEAD + h) * HDP + d] = (bf16)v;
          } else if (part == 1) {
            kpad[(m * NHEAD + h) * HDP + d] = (bf16)v;
          } else {
            long long c = m >> 10, t = m & 1023;
            vt[((c * NHEAD + h) * HD + d) * CHUNK + t] = (bf16)v;
          }
        }
      }
    }
  } else {
#pragma unroll
    for (int jt = 0; jt < 4; ++jt) {
      int n = (int)n0 + wc * 64 + jt * 16 + l16;
      float bv = bias[n];
#pragma unroll
      for (int it = 0; it < 4; ++it) {
#pragma unroll
        for (int r = 0; r < 4; ++r) {
          long long m = m0 + wr * 64 + it * 16 + quad * 4 + r;
          outF[m * HID + n] = acc[it][jt][r] + bv;
        }
      }
    }
  }
}

// ---------------------------------------------------------------------------
// Kernel 3: RoPE in-place, vectorized bf16x8.
// ---------------------------------------------------------------------------
__global__ void rope_kernel(const float* __restrict__ cosp,
                            const float* __restrict__ sinp,
                            bf16* __restrict__ ws) {
  long long i = (long long)blockIdx.x * 256 + threadIdx.x;
  int g = (int)(i % 5);
  long long r = i / 5;
  int h = (int)(r % NHEAD);
  long long r2 = r / NHEAD;
  int tok = (int)(r2 % S_LEN);
  int isK = (int)(r2 / S_LEN);
  bf16* base = ws + (isK ? OFF_KPAD : OFF_QPAD) + ((long long)tok * NHEAD + h) * HDP;
  bf16x8 a8 = *(const bf16x8*)(base + g * 8);
  bf16x8 b8 = *(const bf16x8*)(base + 40 + g * 8);
  const float* cb = cosp + (long long)tok * HD;
  const float* sb = sinp + (long long)tok * HD;
  bf16x8 oA, oB;
#pragma unroll
  for (int j = 0; j < 8; ++j) {
    float a = (float)a8[j], b = (float)b8[j];
    int d = g * 8 + j;
    oA[j] = (bf16)(a * cb[d] - b * sb[d]);
    oB[j] = (bf16)(b * cb[d + 40] + a * sb[d + 40]);
  }
  *(bf16x8*)(base + g * 8) = oA;
  *(bf16x8*)(base + 40 + g * 8) = oB;
}

// ---------------------------------------------------------------------------
// Kernel 4: flash attention per (chunk, head). Q-tile 128 (32 rows/wave),
// K-tile 64. Fixed-max softmax (scores ~N(0,0.5)): P = exp(s), single final
// row-sum. DOUBLE-BUFFERED K/V staging, ONE barrier per tile: the vmcnt(0)
// drain overlaps a full tile's compute (S-MFMA + exp + Ps + PV-MFMA).
// LDS: 2*(13312+14336) + 22528 = 77824 B -> 2 blocks/CU.
// ---------------------------------------------------------------------------
__global__ __launch_bounds__(256, 2) void attn_kernel(bf16* __restrict__ ws) {
  __shared__ __align__(16) bf16 Ks[2][64 * 104];       // 13312 B each
  __shared__ __align__(16) bf16 Vs[2][80 * 88 + 128];  // 14336 B each
  __shared__ __align__(16) bf16 Ps[128 * 88];          // 22528 B
  const int qt = blockIdx.x, h = blockIdx.y, c = blockIdx.z;
  const int tid = threadIdx.x, lane = tid & 63, w = tid >> 6;
  const int quad = lane >> 4, l16 = lane & 15;

  const bf16* qpad = ws + OFF_QPAD;
  const bf16* kpad = ws + OFF_KPAD;
  const bf16* vt = ws + OFF_VT;
  bf16* attn = ws + OFF_ATTN;

  // --- staging source precompute ---
  // K image: 64 rows x 208 B (192 real) = 832 chunks, 13/row
  const char* kbase =
      (const char*)(kpad + (((long long)c * CHUNK) * NHEAD + h) * HDP);
  const char* ksrc[4];
#pragma unroll
  for (int j = 0; j < 4; ++j) {
    int ci = tid + j * 256;
    int ciq = ci < 832 ? ci : 831;
    int row = ciq / 13;
    int cb = (ciq - row * 13) * 16;
    if (cb >= 192) cb = 0;
    ksrc[j] = kbase + row * 3072 + cb;
  }
  // V image: 80 rows x 176 B (128 real) = 880 chunks (+16 pad), 11/row
  const char* vbase = (const char*)(vt + ((long long)c * NHEAD + h) * HD * CHUNK);
  const char* vsrc[4];
#pragma unroll
  for (int j = 0; j < 4; ++j) {
    int ci = tid + j * 256;
    int row = ci / 11;
    if (row > 79) row = 79;
    int cb = (ci - row * 11) * 16;
    if (cb >= 128) cb = 0;
    vsrc[j] = vbase + row * 2048 + cb;
  }
  const int wb = w * 64 * 16;  // wave-uniform chunk base (byte)

  // prologue: stage tile 0 into buffer 0
  {
#pragma unroll
    for (int j = 0; j < 3; ++j)
      gl_lds16(ksrc[j], (char*)Ks[0] + j * 4096 + wb);
    if (tid < 64) gl_lds16(ksrc[3], (char*)Ks[0] + 3 * 4096 + wb);
#pragma unroll
    for (int j = 0; j < 3; ++j)
      gl_lds16(vsrc[j], (char*)Vs[0] + j * 4096 + wb);
    if (tid < 128) gl_lds16(vsrc[3], (char*)Vs[0] + 3 * 4096 + wb);
  }

  // --- Q fragments, pre-scaled (overlaps the prologue DMA) ---
  const float scale = 0.111803398875f;  // 1/sqrt(80)
  bf16x8 qf[2][3];
#pragma unroll
  for (int it = 0; it < 2; ++it) {
    long long tok = (long long)c * CHUNK + qt * 128 + w * 32 + it * 16 + l16;
    const bf16* qrow = qpad + (tok * NHEAD + h) * HDP;
#pragma unroll
    for (int ks = 0; ks < 3; ++ks) {
      bf16x8 t = *(const bf16x8*)(qrow + ks * 32 + quad * 8);
#pragma unroll
      for (int j = 0; j < 8; ++j) t[j] = (bf16)((float)t[j] * scale);
      qf[it][ks] = t;
    }
  }

  f32x4 o[2][5] = {};
  float lrow[2][4] = {};

  for (int t = 0; t < 16; ++t) {
    const int cur = t & 1;
    __syncthreads();  // drains vmcnt -> buf[cur] ready; readers done with buf[cur^1]
    if (t + 1 < 16) {
      const int kadv = (t + 1) * 64 * 3072;   // K bytes per 64-key tile step
      const int vadv = (t + 1) * 64 * 2;      // V^T bytes per tile step
#pragma unroll
      for (int j = 0; j < 3; ++j)
        gl_lds16(ksrc[j] + kadv, (char*)Ks[cur ^ 1] + j * 4096 + wb);
      if (tid < 64) gl_lds16(ksrc[3] + kadv, (char*)Ks[cur ^ 1] + 3 * 4096 + wb);
#pragma unroll
      for (int j = 0; j < 3; ++j)
        gl_lds16(vsrc[j] + vadv, (char*)Vs[cur ^ 1] + j * 4096 + wb);
      if (tid < 128) gl_lds16(vsrc[3] + vadv, (char*)Vs[cur ^ 1] + 3 * 4096 + wb);
    }
    const bf16* K_ = Ks[cur];
    const bf16* V_ = Vs[cur];

    // S = Q K^T, exp, Ps write (wave-private rows w*32..w*32+31)
#pragma unroll
    for (int jt = 0; jt < 4; ++jt) {
      bf16x8 kb[3];
#pragma unroll
      for (int ks = 0; ks < 3; ++ks)
        kb[ks] = *(const bf16x8*)(K_ + (jt * 16 + l16) * 104 + ks * 32 + quad * 8);
#pragma unroll
      for (int it = 0; it < 2; ++it) {
        f32x4 z = {};
#pragma unroll
        for (int ks = 0; ks < 3; ++ks)
          z = __builtin_amdgcn_mfma_f32_16x16x32_bf16(qf[it][ks], kb[ks], z, 0, 0, 0);
#pragma unroll
        for (int r = 0; r < 4; ++r) {
          float p = __expf(z[r]);
          lrow[it][r] += p;
          Ps[(w * 32 + it * 16 + quad * 4 + r) * 88 + jt * 16 + l16] = (bf16)p;
        }
      }
    }

    // O += P V (Ps same-wave write->read; compiler inserts lgkmcnt wait)
#pragma unroll
    for (int k2 = 0; k2 < 2; ++k2) {
      bf16x8 pa[2];
#pragma unroll
      for (int it = 0; it < 2; ++it)
        pa[it] = *(const bf16x8*)(Ps + (w * 32 + it * 16 + l16) * 88 + k2 * 32 + quad * 8);
#pragma unroll
      for (int ct = 0; ct < 5; ++ct) {
        bf16x8 vb = *(const bf16x8*)(V_ + (ct * 16 + l16) * 88 + k2 * 32 + quad * 8);
#pragma unroll
        for (int it = 0; it < 2; ++it)
          o[it][ct] = __builtin_amdgcn_mfma_f32_16x16x32_bf16(pa[it], vb, o[it][ct], 0, 0, 0);
      }
    }
  }

  // final row-sum reduce (over l16) and write
#pragma unroll
  for (int it = 0; it < 2; ++it) {
#pragma unroll
    for (int r = 0; r < 4; ++r) {
      float l = lrow[it][r];
      l += __shfl_xor(l, 1, 64);
      l += __shfl_xor(l, 2, 64);
      l += __shfl_xor(l, 4, 64);
      l += __shfl_xor(l, 8, 64);
      float rinv = 1.0f / l;
      long long tok = (long long)c * CHUNK + qt * 128 + w * 32 + it * 16 + quad * 4 + r;
#pragma unroll
      for (int ct = 0; ct < 5; ++ct)
        attn[tok * HID + h * HD + ct * 16 + l16] = (bf16)(o[it][ct][r] * rinv);
    }
  }
}

// ---------------------------------------------------------------------------
extern "C" void kernel_launch(void* const* d_in, const int* in_sizes, int n_in,
                              void* d_out, int out_size, void* d_ws,
                              size_t ws_size, hipStream_t stream) {
  const float* x = (const float*)d_in[0];
  const float* cosp = (const float*)d_in[2];
  const float* sinp = (const float*)d_in[3];
  const float* wqkv = (const float*)d_in[4];
  const float* bqkv = (const float*)d_in[5];
  const float* wproj = (const float*)d_in[6];
  const float* bproj = (const float*)d_in[7];
  bf16* ws = (bf16*)d_ws;
  float* out = (float*)d_out;

  convert_kernel<<<35072, 256, 0, stream>>>(x, wqkv, wproj, ws);
  gemm_bt_kernel<0><<<dim3(30, 128), 256, 0, stream>>>(
      ws + OFF_XB, ws + OFF_WQKV, bqkv, ws, nullptr);
  rope_kernel<<<10240, 256, 0, stream>>>(cosp, sinp, ws);
  attn_kernel<<<dim3(8, 16, 16), 256, 0, stream>>>(ws);
  gemm_bt_kernel<1><<<dim3(10, 128), 256, 0, stream>>>(
      ws + OFF_ATTN, ws + OFF_WPROJ, bproj, ws, out);
}

// Round 5
// 754.776 us; speedup vs baseline: 1.0199x; 1.0199x over previous
//
#include <hip/hip_runtime.h>
#include <cstdint>

typedef __bf16 bf16;
typedef bf16 bf16x8 __attribute__((ext_vector_type(8)));
typedef float f32x4 __attribute__((ext_vector_type(4)));

#define S_LEN   16384
#define HID     1280
#define NHEAD   16
#define HD      80
#define HDP     96
#define CHUNK   1024
#define NCHUNKS 16

// workspace element offsets (bf16 elements)
#define OFF_XB     0LL           // x bf16            [16384][1280]
#define OFF_WQKV   20971520LL    // w_qkv bf16        [3840][1280]
#define OFF_WPROJ  25886720LL    // w_proj bf16       [1280][1280]
#define OFF_QPAD   27525120LL    // q bf16 padded     [16384][16][96]
#define OFF_KPAD   52690944LL    // k bf16 padded     [16384][16][96]
#define OFF_VT     77856768LL    // v^T bf16          [16][16][80][1024]
#define OFF_ATTN   98828288LL    // attn out bf16     [16384][1280]

// global -> LDS direct copy, 16 B per lane; lane i lands at base + i*16.
__device__ __forceinline__ void gl_lds16(const void* g, void* l) {
  __builtin_amdgcn_global_load_lds(
      (const __attribute__((address_space(1))) unsigned int*)g,
      (__attribute__((address_space(3))) unsigned int*)l, 16, 0, 0);
}

// ---------------------------------------------------------------------------
// Kernel 1: fp32 -> bf16 conversion + zero-fill of q/k pad dims (80..95)
// ---------------------------------------------------------------------------
__global__ void convert_kernel(const float* __restrict__ x,
                               const float* __restrict__ wqkv,
                               const float* __restrict__ wproj,
                               bf16* __restrict__ ws) {
  const long long N1 = 20971520LL;
  const long long N2 = 4915200LL;
  const long long N3 = 1638400LL;
  const long long N4 = 4194304LL;
  long long i = ((long long)blockIdx.x * 256 + threadIdx.x) << 2;
  if (i < N1) {
    float4 v = *(const float4*)(x + i);
    bf16* o = ws + OFF_XB + i;
    o[0] = (bf16)v.x; o[1] = (bf16)v.y; o[2] = (bf16)v.z; o[3] = (bf16)v.w;
    return;
  }
  i -= N1;
  if (i < N2) {
    float4 v = *(const float4*)(wqkv + i);
    bf16* o = ws + OFF_WQKV + i;
    o[0] = (bf16)v.x; o[1] = (bf16)v.y; o[2] = (bf16)v.z; o[3] = (bf16)v.w;
    return;
  }
  i -= N2;
  if (i < N3) {
    float4 v = *(const float4*)(wproj + i);
    bf16* o = ws + OFF_WPROJ + i;
    o[0] = (bf16)v.x; o[1] = (bf16)v.y; o[2] = (bf16)v.z; o[3] = (bf16)v.w;
    return;
  }
  i -= N3;
  if (i < N4) {
    long long g = i >> 4; int j = (int)(i & 15);
    *(uint2*)(ws + OFF_QPAD + g * HDP + HD + j) = make_uint2(0u, 0u);
    return;
  }
  i -= N4;
  if (i < N4) {
    long long g = i >> 4; int j = (int)(i & 15);
    *(uint2*)(ws + OFF_KPAD + g * HDP + HD + j) = make_uint2(0u, 0u);
    return;
  }
}

// ---------------------------------------------------------------------------
// Kernels 2 & 5: bf16 GEMM C = A @ B^T (+bias). BM=256 x BN=128, BK=32,
// double-buffered global_load_lds staging. Grid: blockIdx.x = M-strip
// (fast-varying) so the ~30 blocks sharing one A-strip all have linear ids
// congruent mod 8 -> same XCD -> A-strip fetched once per XCD L2 (XCD
// round-robin by dispatch id). Wave-tile 128x64 (it=8, jt=4).
// LDS 2 x 30720 B -> 2 blocks/CU; padded stride-40 rows (20 dw == 4 mod 32).
// ---------------------------------------------------------------------------
template <int MODE>
__global__ __launch_bounds__(256, 2) void gemm_bt_kernel(
    const bf16* __restrict__ A, const bf16* __restrict__ B,
    const float* __restrict__ bias, bf16* __restrict__ ws,
    float* __restrict__ outF) {
  __shared__ __align__(16) bf16 ABs[2][15360];  // A[256][40] then B[128][40]
  const int tid = threadIdx.x;
  const int lane = tid & 63;
  const int w = tid >> 6;
  const int wr = w >> 1, wc = w & 1;          // wave row (0,1) / col (0,1)
  const int quad = lane >> 4, l16 = lane & 15;
  const long long m0 = (long long)blockIdx.x * 256;   // x = M (fast) for XCD locality
  const long long n0 = (long long)blockIdx.y * 128;

  // staging sources: A image 256 rows x 5 chunks (4 real + 1 pad) = 1280,
  // B image 128 rows x 5 chunks = 640 (rounds 5,6 full; round 7 tid<128)
  const bf16* gsrcA[5];
#pragma unroll
  for (int j = 0; j < 5; ++j) {
    int ci = tid + j * 256;
    int row = ci / 5;
    int cb = ci - row * 5;                  // chunk-in-row 0..4 (4 = pad)
    int ce = (cb == 4) ? 0 : cb * 8;
    gsrcA[j] = A + (m0 + row) * 1280 + ce;
  }
  const bf16* gsrcB[3];
#pragma unroll
  for (int j = 0; j < 3; ++j) {
    int ci = tid + j * 256;
    if (ci > 639) ci = 639;
    int row = ci / 5;
    int cb = ci - row * 5;
    int ce = (cb == 4) ? 0 : cb * 8;
    gsrcB[j] = B + (n0 + row) * 1280 + ce;
  }
  const int wb = w * 1024;  // wave-uniform LDS byte base within a round

  // prologue: stage k0=0 into buffer 0
#pragma unroll
  for (int j = 0; j < 5; ++j)
    gl_lds16(gsrcA[j], (char*)ABs[0] + j * 4096 + wb);
#pragma unroll
  for (int j = 0; j < 2; ++j)
    gl_lds16(gsrcB[j], (char*)ABs[0] + 20480 + j * 4096 + wb);
  if (tid < 128) gl_lds16(gsrcB[2], (char*)ABs[0] + 20480 + 8192 + wb);

  f32x4 acc[8][4] = {};

  for (int k0 = 0; k0 < 1280; k0 += 32) {
    const int cur = (k0 >> 5) & 1;
    __syncthreads();  // drains vmcnt -> buf[cur] ready
    if (k0 + 32 < 1280) {
      char* nb = (char*)ABs[cur ^ 1];
#pragma unroll
      for (int j = 0; j < 5; ++j)
        gl_lds16(gsrcA[j] + k0 + 32, nb + j * 4096 + wb);
#pragma unroll
      for (int j = 0; j < 2; ++j)
        gl_lds16(gsrcB[j] + k0 + 32, nb + 20480 + j * 4096 + wb);
      if (tid < 128) gl_lds16(gsrcB[2] + k0 + 32, nb + 20480 + 8192 + wb);
    }
    const bf16* As = ABs[cur];
    const bf16* Bs = ABs[cur] + 10240;
    bf16x8 af[8], bfr[4];
#pragma unroll
    for (int it = 0; it < 8; ++it)
      af[it] = *(const bf16x8*)(As + (wr * 128 + it * 16 + l16) * 40 + quad * 8);
#pragma unroll
    for (int jt = 0; jt < 4; ++jt)
      bfr[jt] = *(const bf16x8*)(Bs + (wc * 64 + jt * 16 + l16) * 40 + quad * 8);
#pragma unroll
    for (int it = 0; it < 8; ++it)
#pragma unroll
      for (int jt = 0; jt < 4; ++jt)
        acc[it][jt] = __builtin_amdgcn_mfma_f32_16x16x32_bf16(
            af[it], bfr[jt], acc[it][jt], 0, 0, 0);
  }

  if (MODE == 0) {
    bf16* qpad = ws + OFF_QPAD;
    bf16* kpad = ws + OFF_KPAD;
    bf16* vt = ws + OFF_VT;
#pragma unroll
    for (int jt = 0; jt < 4; ++jt) {
      int n = (int)n0 + wc * 64 + jt * 16 + l16;
      float bv = bias[n];
      int part = n / HID;
      int idx = n - part * HID;
      int h = idx / HD;
      int d = idx - h * HD;
#pragma unroll
      for (int it = 0; it < 8; ++it) {
#pragma unroll
        for (int r = 0; r < 4; ++r) {
          long long m = m0 + wr * 128 + it * 16 + quad * 4 + r;
          float v = acc[it][jt][r] + bv;
          if (part == 0) {
            qpad[(m * NHEAD + h) * HDP + d] = (bf16)v;
          } else if (part == 1) {
            kpad[(m * NHEAD + h) * HDP + d] = (bf16)v;
          } else {
            long long c = m >> 10, t = m & 1023;
            vt[((c * NHEAD + h) * HD + d) * CHUNK + t] = (bf16)v;
          }
        }
      }
    }
  } else {
#pragma unroll
    for (int jt = 0; jt < 4; ++jt) {
      int n = (int)n0 + wc * 64 + jt * 16 + l16;
      float bv = bias[n];
#pragma unroll
      for (int it = 0; it < 8; ++it) {
#pragma unroll
        for (int r = 0; r < 4; ++r) {
          long long m = m0 + wr * 128 + it * 16 + quad * 4 + r;
          outF[m * HID + n] = acc[it][jt][r] + bv;
        }
      }
    }
  }
}

// ---------------------------------------------------------------------------
// Kernel 3: RoPE in-place, vectorized bf16x8.
// ---------------------------------------------------------------------------
__global__ void rope_kernel(const float* __restrict__ cosp,
                            const float* __restrict__ sinp,
                            bf16* __restrict__ ws) {
  long long i = (long long)blockIdx.x * 256 + threadIdx.x;
  int g = (int)(i % 5);
  long long r = i / 5;
  int h = (int)(r % NHEAD);
  long long r2 = r / NHEAD;
  int tok = (int)(r2 % S_LEN);
  int isK = (int)(r2 / S_LEN);
  bf16* base = ws + (isK ? OFF_KPAD : OFF_QPAD) + ((long long)tok * NHEAD + h) * HDP;
  bf16x8 a8 = *(const bf16x8*)(base + g * 8);
  bf16x8 b8 = *(const bf16x8*)(base + 40 + g * 8);
  const float* cb = cosp + (long long)tok * HD;
  const float* sb = sinp + (long long)tok * HD;
  bf16x8 oA, oB;
#pragma unroll
  for (int j = 0; j < 8; ++j) {
    float a = (float)a8[j], b = (float)b8[j];
    int d = g * 8 + j;
    oA[j] = (bf16)(a * cb[d] - b * sb[d]);
    oB[j] = (bf16)(b * cb[d + 40] + a * sb[d + 40]);
  }
  *(bf16x8*)(base + g * 8) = oA;
  *(bf16x8*)(base + 40 + g * 8) = oB;
}

// ---------------------------------------------------------------------------
// Kernel 4: flash attention. Q-tile 256 (64 rows/wave, it=4), K-tile 64,
// 4 q-blocks per (chunk,head) -> K/V re-read 4x (was 8x). Grid x = (c,h)
// so the 4 sharers have ids congruent mod 8 -> same XCD L2. Fixed-max
// softmax; double-buffered K/V DMA staging; one barrier per tile; per
// barrier: 88 MFMA + 64 exp per wave vs 27.6 KB staged.
// LDS 26.6+28.7+45 KB = 100 KB -> 1 block/CU.
// ---------------------------------------------------------------------------
__global__ __launch_bounds__(256, 1) void attn_kernel(bf16* __restrict__ ws) {
  __shared__ __align__(16) bf16 Ks[2][64 * 104];       // 13312 B each
  __shared__ __align__(16) bf16 Vs[2][80 * 88 + 128];  // 14336 B each
  __shared__ __align__(16) bf16 Ps[256 * 88];          // 45056 B
  const int ch = blockIdx.x;
  const int c = ch >> 4, h = ch & 15;
  const int qt = blockIdx.y;
  const int tid = threadIdx.x, lane = tid & 63, w = tid >> 6;
  const int quad = lane >> 4, l16 = lane & 15;

  const bf16* qpad = ws + OFF_QPAD;
  const bf16* kpad = ws + OFF_KPAD;
  const bf16* vt = ws + OFF_VT;
  bf16* attn = ws + OFF_ATTN;

  // --- staging source precompute ---
  // K image: 64 rows x 208 B (192 real) = 832 chunks, 13/row
  const char* kbase =
      (const char*)(kpad + (((long long)c * CHUNK) * NHEAD + h) * HDP);
  const char* ksrc[4];
#pragma unroll
  for (int j = 0; j < 4; ++j) {
    int ci = tid + j * 256;
    int ciq = ci < 832 ? ci : 831;
    int row = ciq / 13;
    int cb = (ciq - row * 13) * 16;
    if (cb >= 192) cb = 0;
    ksrc[j] = kbase + row * 3072 + cb;
  }
  // V image: 80 rows x 176 B (128 real) = 880 chunks (+16 slack), 11/row
  const char* vbase = (const char*)(vt + ((long long)c * NHEAD + h) * HD * CHUNK);
  const char* vsrc[4];
#pragma unroll
  for (int j = 0; j < 4; ++j) {
    int ci = tid + j * 256;
    int row = ci / 11;
    if (row > 79) row = 79;
    int cb = (ci - row * 11) * 16;
    if (cb >= 128) cb = 0;
    vsrc[j] = vbase + row * 2048 + cb;
  }
  const int wb = w * 1024;  // wave-uniform chunk base (byte)

  // prologue: stage tile 0 into buffer 0
  {
#pragma unroll
    for (int j = 0; j < 3; ++j)
      gl_lds16(ksrc[j], (char*)Ks[0] + j * 4096 + wb);
    if (tid < 64) gl_lds16(ksrc[3], (char*)Ks[0] + 3 * 4096 + wb);
#pragma unroll
    for (int j = 0; j < 3; ++j)
      gl_lds16(vsrc[j], (char*)Vs[0] + j * 4096 + wb);
    if (tid < 128) gl_lds16(vsrc[3], (char*)Vs[0] + 3 * 4096 + wb);
  }

  // --- Q fragments, pre-scaled (overlaps the prologue DMA) ---
  const float scale = 0.111803398875f;  // 1/sqrt(80)
  bf16x8 qf[4][3];
#pragma unroll
  for (int it = 0; it < 4; ++it) {
    long long tok = (long long)c * CHUNK + qt * 256 + w * 64 + it * 16 + l16;
    const bf16* qrow = qpad + (tok * NHEAD + h) * HDP;
#pragma unroll
    for (int ks = 0; ks < 3; ++ks) {
      bf16x8 t = *(const bf16x8*)(qrow + ks * 32 + quad * 8);
#pragma unroll
      for (int j = 0; j < 8; ++j) t[j] = (bf16)((float)t[j] * scale);
      qf[it][ks] = t;
    }
  }

  f32x4 o[4][5] = {};
  float lrow[4][4] = {};

  for (int t = 0; t < 16; ++t) {
    const int cur = t & 1;
    __syncthreads();  // drains vmcnt -> buf[cur] ready; readers done with buf[cur^1]
    if (t + 1 < 16) {
      const int kadv = (t + 1) * 64 * 3072;   // K bytes per 64-key tile step
      const int vadv = (t + 1) * 64 * 2;      // V^T bytes per tile step
#pragma unroll
      for (int j = 0; j < 3; ++j)
        gl_lds16(ksrc[j] + kadv, (char*)Ks[cur ^ 1] + j * 4096 + wb);
      if (tid < 64) gl_lds16(ksrc[3] + kadv, (char*)Ks[cur ^ 1] + 3 * 4096 + wb);
#pragma unroll
      for (int j = 0; j < 3; ++j)
        gl_lds16(vsrc[j] + vadv, (char*)Vs[cur ^ 1] + j * 4096 + wb);
      if (tid < 128) gl_lds16(vsrc[3] + vadv, (char*)Vs[cur ^ 1] + 3 * 4096 + wb);
    }
    const bf16* K_ = Ks[cur];
    const bf16* V_ = Vs[cur];

    // S = Q K^T, exp, Ps write (wave-private rows w*64..w*64+63)
#pragma unroll
    for (int jt = 0; jt < 4; ++jt) {
      bf16x8 kb[3];
#pragma unroll
      for (int ks = 0; ks < 3; ++ks)
        kb[ks] = *(const bf16x8*)(K_ + (jt * 16 + l16) * 104 + ks * 32 + quad * 8);
#pragma unroll
      for (int it = 0; it < 4; ++it) {
        f32x4 z = {};
#pragma unroll
        for (int ks = 0; ks < 3; ++ks)
          z = __builtin_amdgcn_mfma_f32_16x16x32_bf16(qf[it][ks], kb[ks], z, 0, 0, 0);
#pragma unroll
        for (int r = 0; r < 4; ++r) {
          float p = __expf(z[r]);
          lrow[it][r] += p;
          Ps[(w * 64 + it * 16 + quad * 4 + r) * 88 + jt * 16 + l16] = (bf16)p;
        }
      }
    }

    // O += P V (Ps same-wave write->read; compiler inserts lgkmcnt wait)
#pragma unroll
    for (int k2 = 0; k2 < 2; ++k2) {
      bf16x8 pa[4];
#pragma unroll
      for (int it = 0; it < 4; ++it)
        pa[it] = *(const bf16x8*)(Ps + (w * 64 + it * 16 + l16) * 88 + k2 * 32 + quad * 8);
#pragma unroll
      for (int ct = 0; ct < 5; ++ct) {
        bf16x8 vb = *(const bf16x8*)(V_ + (ct * 16 + l16) * 88 + k2 * 32 + quad * 8);
#pragma unroll
        for (int it = 0; it < 4; ++it)
          o[it][ct] = __builtin_amdgcn_mfma_f32_16x16x32_bf16(pa[it], vb, o[it][ct], 0, 0, 0);
      }
    }
  }

  // final row-sum reduce (over l16) and write
#pragma unroll
  for (int it = 0; it < 4; ++it) {
#pragma unroll
    for (int r = 0; r < 4; ++r) {
      float l = lrow[it][r];
      l += __shfl_xor(l, 1, 64);
      l += __shfl_xor(l, 2, 64);
      l += __shfl_xor(l, 4, 64);
      l += __shfl_xor(l, 8, 64);
      float rinv = 1.0f / l;
      long long tok = (long long)c * CHUNK + qt * 256 + w * 64 + it * 16 + quad * 4 + r;
#pragma unroll
      for (int ct = 0; ct < 5; ++ct)
        attn[tok * HID + h * HD + ct * 16 + l16] = (bf16)(o[it][ct][r] * rinv);
    }
  }
}

// ---------------------------------------------------------------------------
extern "C" void kernel_launch(void* const* d_in, const int* in_sizes, int n_in,
                              void* d_out, int out_size, void* d_ws,
                              size_t ws_size, hipStream_t stream) {
  const float* x = (const float*)d_in[0];
  const float* cosp = (const float*)d_in[2];
  const float* sinp = (const float*)d_in[3];
  const float* wqkv = (const float*)d_in[4];
  const float* bqkv = (const float*)d_in[5];
  const float* wproj = (const float*)d_in[6];
  const float* bproj = (const float*)d_in[7];
  bf16* ws = (bf16*)d_ws;
  float* out = (float*)d_out;

  convert_kernel<<<35072, 256, 0, stream>>>(x, wqkv, wproj, ws);
  gemm_bt_kernel<0><<<dim3(64, 30), 256, 0, stream>>>(
      ws + OFF_XB, ws + OFF_WQKV, bqkv, ws, nullptr);
  rope_kernel<<<10240, 256, 0, stream>>>(cosp, sinp, ws);
  attn_kernel<<<dim3(256, 4), 256, 0, stream>>>(ws);
  gemm_bt_kernel<1><<<dim3(64, 10), 256, 0, stream>>>(
      ws + OFF_ATTN, ws + OFF_WPROJ, bproj, ws, out);
}